// Round 5
// baseline (117.252 us; speedup 1.0000x reference)
//
#include <hip/hip_runtime.h>
#include <hip/hip_bf16.h>
#include <math.h>

#define NH 16
#define QL 2048
#define SL 2048
#define DD 64
#define BQ 256
#define NSPLIT 4
#define PSTR 72
#define QK_SCALE_LOG2E 0.1803368801111f   // (8/64) * log2(e): fold softmax scale + ln2 into Q

typedef __attribute__((ext_vector_type(8))) short short8;
typedef __attribute__((ext_vector_type(4))) float floatx4;
typedef __attribute__((ext_vector_type(4))) unsigned short ushort4v;
typedef __attribute__((ext_vector_type(8))) unsigned short ushort8v;

__device__ __forceinline__ unsigned short f2bf(float x) {   // RNE fp32->bf16
    unsigned u = __float_as_uint(x);
    u += 0x7FFFu + ((u >> 16) & 1u);
    return (unsigned short)(u >> 16);
}
__device__ __forceinline__ unsigned int f2bf2u(float x, float y) {  // packed pair (low=x)
    __hip_bfloat162 h = __float22bfloat162_rn(make_float2(x, y));
    return *(unsigned int*)&h;
}
__device__ __forceinline__ float bf2f(unsigned short h) {
    return __uint_as_float((unsigned)h << 16);
}

// async global->LDS, 16B per lane; LDS dest = wave-uniform base + lane*16
__device__ __forceinline__ void gld16(const unsigned short* g, unsigned short* l) {
    __builtin_amdgcn_global_load_lds(
        (const __attribute__((address_space(1))) unsigned int*)g,
        (__attribute__((address_space(3))) unsigned int*)l, 16, 0, 0);
}

// ---------------- prep: Q->bf16(prescaled) + K->bf16 + V->V^T bf16, one 512x512 launch ----------------
__global__ __launch_bounds__(512) void k_prep(
    const float* __restrict__ Qf, const float* __restrict__ Kf, const float* __restrict__ Vf,
    unsigned short* __restrict__ Qb, unsigned short* __restrict__ Kb, unsigned short* __restrict__ Vtb)
{
    __shared__ unsigned short sT[64][PSTR];    // 9 KB: V-transpose scratch
    const int bx = (int)blockIdx.x, tid = (int)threadIdx.x;
    const int gidx = bx * 512 + tid;

    // K convert: NH*SL*DD/4 = 524288 float4 groups, 2 per thread
    #pragma unroll
    for (int k = 0; k < 2; ++k) {
        int idx = gidx + k * (512 * 512);
        float4 v = ((const float4*)Kf)[idx];
        ushort4v h = { f2bf(v.x), f2bf(v.y), f2bf(v.z), f2bf(v.w) };
        *(ushort4v*)(Kb + (size_t)idx * 4) = h;
    }
    // Q convert with softmax scale folded (exactly matches prior in-attn conversion numerics)
    #pragma unroll
    for (int k = 0; k < 2; ++k) {
        int idx = gidx + k * (512 * 512);
        float4 v = ((const float4*)Qf)[idx];
        const float S = QK_SCALE_LOG2E;
        ushort4v h = { f2bf(v.x * S), f2bf(v.y * S), f2bf(v.z * S), f2bf(v.w * S) };
        *(ushort4v*)(Qb + (size_t)idx * 4) = h;
    }

    // V transpose: block bx owns s-tile bx (16 heads x 32 tiles = 512)
    const int n = bx >> 5, s0 = (bx & 31) * 64;
    const float* vb = Vf + ((size_t)n * SL + s0) * DD;
    #pragma unroll
    for (int i = 0; i < 2; ++i) {
        int idx = tid + i * 512;
        int r = idx >> 4, c = (idx & 15) << 2;
        float4 v = *(const float4*)(vb + r * DD + c);
        sT[c + 0][r] = f2bf(v.x);
        sT[c + 1][r] = f2bf(v.y);
        sT[c + 2][r] = f2bf(v.z);
        sT[c + 3][r] = f2bf(v.w);
    }
    __syncthreads();
    const int d = tid >> 3, sg = tid & 7;
    unsigned short* out = Vtb + (size_t)n * DD * SL + (size_t)d * SL + s0 + sg * 8;
    ushort8v a;
    #pragma unroll
    for (int i = 0; i < 8; ++i) a[i] = sT[d][sg * 8 + i];
    *(ushort8v*)out = a;
}

// ---------------- attention: BQ=256 (2 q-halves/wave), 8 waves, parity-4 split-S, 3-buf pipeline ----------
// Split sp owns s-tiles with (tile & 3) == sp. Diag tiles d0..d0+3 (d0 = q0/64, multiple of 4) give
// each split EXACTLY one diag tile -> every block has >= 1 tile, combine is unconditional.
// Each wave holds TWO 16-row Q fragments; K/V LDS fragments are loaded once and feed 2 MFMAs each,
// halving LDS-read bytes per MFMA vs BQ=128.
__global__ __launch_bounds__(512, 4) void k_attn(
    const unsigned short* __restrict__ Qb, const unsigned short* __restrict__ Kb,
    const unsigned short* __restrict__ Vtb, const int* __restrict__ plen_g,
    unsigned short* __restrict__ Opb, float* __restrict__ Lp)
{
    // K/V: 64x64 bf16 tiles, row = 64 ushorts (128B, NO pad: global_load_lds needs lane*16 dest),
    // chunk c of row r at slot c ^ (r&7) (swizzle on the global fetch side).
    __shared__ unsigned short sK[3][64 * 64];     // 24 KB: triple-buffered, prefetch distance 2
    __shared__ unsigned short sVt[3][64 * 64];    // 24 KB
    __shared__ unsigned short sP[2][8 * 16 * 64]; // 32 KB: per-q-half P (wave-private rows)

    const int flat = (int)blockIdx.x;
    const int sp   = flat >> 7;                // parity-4 split 0..3
    const int rb   = flat & 127;
    const int n    = (rb + sp) & (NH - 1);     // head remap (bijective per split)
    const int qt   = rb >> 4;                  // 0..7
    const int q0   = qt * BQ;
    const int plen = plen_g[n];

    const int tid  = (int)threadIdx.x;
    const int wave = tid >> 6, lane = tid & 63, quad = lane >> 4, l16 = lane & 15;

    const int ptiles = (plen + 63) >> 6;       // 0..32 prefix tiles (last may be partial)
    const int d0     = q0 >> 6;                // multiple of 4
    const int tdiag  = d0 + sp;                // the parity-sp diag tile (one per split)
    const int cnt_p  = (ptiles + 3 - sp) >> 2; // # parity-sp prefix tiles
    const int total  = cnt_p + (tdiag >= ptiles ? 1 : 0);   // >= 1 always

    const int qrow  = wave * 16 + l16;         // local q row within half (0..127)
    const int qgA   = q0 + qrow;               // q-half A global row
    const int qgB   = qgA + 128;               // q-half B global row
    const int pmask = (l16 & 7) * 8;           // sP XOR swizzle (bits 3-5; b128-safe)

    const unsigned short* kh = Kb  + (size_t)n * SL * DD;
    const unsigned short* vh = Vtb + (size_t)n * DD * SL;

    // staging lane mapping: each of 8 waves moves one 1KB segment of K and of V per tile
    const int srow = wave * 8 + (lane >> 3);
    const int scol = ((lane & 7) ^ (srow & 7)) * 8;

    auto tile_of = [&](int i) -> int {
        return (i < cnt_p) ? (sp + (i << 2)) : tdiag;
    };
    // stage tile t into buffer b: exactly 2 global_load_lds per wave (K seg + V seg), uniform
    auto stage = [&](int t, int b) {
        const unsigned short* kg = kh + ((size_t)t << 6) * DD;
        const unsigned short* vg = vh + (t << 6);
        gld16(kg + srow * DD + scol, sK[b] + wave * 512);
        gld16(vg + (size_t)srow * SL + scol, sVt[b] + wave * 512);
    };

    // Q fragments (bf16, prescaled in prep): 2 per half; loaded BEFORE stages so the
    // compiler's wait on their first use drains them while stage-loads stay in flight.
    const unsigned short* qbA = Qb + ((size_t)n * QL + qgA) * DD;
    const unsigned short* qbB = qbA + 128 * DD;
    short8 bQ0A = *(const short8*)(qbA + quad * 8);
    short8 bQ1A = *(const short8*)(qbA + 32 + quad * 8);
    short8 bQ0B = *(const short8*)(qbB + quad * 8);
    short8 bQ1B = *(const short8*)(qbB + 32 + quad * 8);

    // ---- prologue: stage tiles 0 and 1 (distance-2 pipeline fill) ----
    stage(tile_of(0), 0);
    if (total > 1) stage(tile_of(1), 1);

    floatx4 accA[4], accB[4];
    #pragma unroll
    for (int dt = 0; dt < 4; ++dt) {
        accA[dt] = (floatx4){0.f, 0.f, 0.f, 0.f};
        accB[dt] = (floatx4){0.f, 0.f, 0.f, 0.f};
    }
    float lsumA = 0.f, lsumB = 0.f;            // per-lane l partials for rows qgA / qgB
    unsigned short* pwA = sP[0] + qrow * 64;
    unsigned short* pwB = sP[1] + qrow * 64;

    int bi = 0;                                // buffer holding tile i
    int bs = 2;                                // buffer for tile i+2
    for (int i = 0; i < total; ++i) {
        // counted wait: my iter-i pair are the oldest outstanding vmem ops; keep next pair in flight.
        if (i + 2 <= total) {
            asm volatile("s_waitcnt vmcnt(2) lgkmcnt(0)" ::: "memory");
        } else {
            asm volatile("s_waitcnt vmcnt(0) lgkmcnt(0)" ::: "memory");
        }
        __builtin_amdgcn_s_barrier();          // all waves' iter-i loads now landed

        if (i + 2 < total) stage(tile_of(i + 2), bs);   // block-uniform condition

        const unsigned short* sk = sK[bi];
        const unsigned short* sv = sVt[bi];
        const int t  = tile_of(i);
        const int s0 = t << 6;

        // ---- S^T = K·Q^T for both q-halves: K frags loaded ONCE, used twice ----
        floatx4 sfA[4], sfB[4];
        #pragma unroll
        for (int st2 = 0; st2 < 4; ++st2) {
            sfA[st2] = (floatx4){0.f, 0.f, 0.f, 0.f};
            sfB[st2] = (floatx4){0.f, 0.f, 0.f, 0.f};
        }
        __builtin_amdgcn_s_setprio(1);
        #pragma unroll
        for (int st2 = 0; st2 < 4; ++st2) {
            int krow = st2 * 16 + l16;
            short8 aK0 = *(const short8*)(sk + krow * 64 + (((0 * 4 + quad) ^ (krow & 7)) * 8));
            short8 aK1 = *(const short8*)(sk + krow * 64 + (((1 * 4 + quad) ^ (krow & 7)) * 8));
            sfA[st2] = __builtin_amdgcn_mfma_f32_16x16x32_bf16(aK0, bQ0A, sfA[st2], 0, 0, 0);
            sfA[st2] = __builtin_amdgcn_mfma_f32_16x16x32_bf16(aK1, bQ1A, sfA[st2], 0, 0, 0);
            sfB[st2] = __builtin_amdgcn_mfma_f32_16x16x32_bf16(aK0, bQ0B, sfB[st2], 0, 0, 0);
            sfB[st2] = __builtin_amdgcn_mfma_f32_16x16x32_bf16(aK1, bQ1B, sfB[st2], 0, 0, 0);
        }
        __builtin_amdgcn_s_setprio(0);

        // ---- fixed-max softmax: p = exp2(prescaled score); no cross-lane ops ----
        if (s0 + 64 <= plen) {                 // fully-valid tile: both halves fast path
            #pragma unroll
            for (int st2 = 0; st2 < 4; ++st2) {
                float a0 = __builtin_amdgcn_exp2f(sfA[st2][0]);
                float a1 = __builtin_amdgcn_exp2f(sfA[st2][1]);
                float a2 = __builtin_amdgcn_exp2f(sfA[st2][2]);
                float a3 = __builtin_amdgcn_exp2f(sfA[st2][3]);
                lsumA += (a0 + a1) + (a2 + a3);
                uint2 pkA = { f2bf2u(a0, a1), f2bf2u(a2, a3) };
                *(uint2*)(pwA + ((st2 * 16 + quad * 4) ^ pmask)) = pkA;   // P^T-pack, swizzled
                float b0 = __builtin_amdgcn_exp2f(sfB[st2][0]);
                float b1 = __builtin_amdgcn_exp2f(sfB[st2][1]);
                float b2 = __builtin_amdgcn_exp2f(sfB[st2][2]);
                float b3 = __builtin_amdgcn_exp2f(sfB[st2][3]);
                lsumB += (b0 + b1) + (b2 + b3);
                uint2 pkB = { f2bf2u(b0, b1), f2bf2u(b2, b3) };
                *(uint2*)(pwB + ((st2 * 16 + quad * 4) ^ pmask)) = pkB;
            }
        } else {                               // partial/diag tile: per-element mask, per half
            #pragma unroll
            for (int st2 = 0; st2 < 4; ++st2) {
                float pa[4], pb[4];
                #pragma unroll
                for (int r2 = 0; r2 < 4; ++r2) {
                    int s = s0 + st2 * 16 + quad * 4 + r2;
                    bool va = (s < plen) || (s == qgA);
                    bool vb = (s < plen) || (s == qgB);
                    pa[r2] = __builtin_amdgcn_exp2f(va ? sfA[st2][r2] : -INFINITY);
                    pb[r2] = __builtin_amdgcn_exp2f(vb ? sfB[st2][r2] : -INFINITY);
                    lsumA += pa[r2];
                    lsumB += pb[r2];
                }
                uint2 pkA = { f2bf2u(pa[0], pa[1]), f2bf2u(pa[2], pa[3]) };
                uint2 pkB = { f2bf2u(pb[0], pb[1]), f2bf2u(pb[2], pb[3]) };
                *(uint2*)(pwA + ((st2 * 16 + quad * 4) ^ pmask)) = pkA;
                *(uint2*)(pwB + ((st2 * 16 + quad * 4) ^ pmask)) = pkB;
            }
        }

        // ---- PV for both halves: V frags loaded ONCE, used twice ----
        __builtin_amdgcn_s_setprio(1);
        #pragma unroll
        for (int ks = 0; ks < 2; ++ks) {
            short8 aPA = *(const short8*)(pwA + ((ks * 32 + quad * 8) ^ pmask));
            short8 aPB = *(const short8*)(pwB + ((ks * 32 + quad * 8) ^ pmask));
            #pragma unroll
            for (int dt = 0; dt < 4; ++dt) {
                int vrow = dt * 16 + l16;
                short8 bV = *(const short8*)(sv + vrow * 64 + (((ks * 4 + quad) ^ (vrow & 7)) * 8));
                accA[dt] = __builtin_amdgcn_mfma_f32_16x16x32_bf16(aPA, bV, accA[dt], 0, 0, 0);
                accB[dt] = __builtin_amdgcn_mfma_f32_16x16x32_bf16(aPB, bV, accB[dt], 0, 0, 0);
            }
        }
        __builtin_amdgcn_s_setprio(0);

        bi = (bi == 2) ? 0 : bi + 1;
        bs = (bs == 2) ? 0 : bs + 1;
    }

    // ---- epilogue: unnormalized partials, bf16, coalesced via per-wave sP transpose (per half) ----
    lsumA += __shfl_xor(lsumA, 16, 64);
    lsumA += __shfl_xor(lsumA, 32, 64);
    lsumB += __shfl_xor(lsumB, 16, 64);
    lsumB += __shfl_xor(lsumB, 32, 64);
    if (quad == 0) {
        Lp[((size_t)sp * NH + n) * QL + qgA] = lsumA;
        Lp[((size_t)sp * NH + n) * QL + qgB] = lsumB;
    }

    unsigned short* pwsA = sP[0] + wave * 16 * 64;   // wave-private regions, free after last PV
    unsigned short* pwsB = sP[1] + wave * 16 * 64;
    #pragma unroll
    for (int dt = 0; dt < 4; ++dt) {
        int chunk = dt * 2 + (l16 >> 3);
        #pragma unroll
        for (int r2 = 0; r2 < 4; ++r2) {
            int row = quad * 4 + r2;
            int sw = ((chunk ^ (row & 7)) * 8) + (l16 & 7);
            pwsA[row * 64 + sw] = f2bf(accA[dt][r2]);
            pwsB[row * 64 + sw] = f2bf(accB[dt][r2]);
        }
    }
    const size_t qbaseA = ((size_t)sp * NH + n) * QL + q0 + wave * 16;
    const size_t qbaseB = qbaseA + 128;
    #pragma unroll
    for (int t2 = 0; t2 < 2; ++t2) {
        int row = t2 * 8 + (lane >> 3);
        int chunk = lane & 7;
        int sw = (chunk ^ (row & 7)) * 8;
        ushort8v valA = *(const ushort8v*)(pwsA + row * 64 + sw);
        ushort8v valB = *(const ushort8v*)(pwsB + row * 64 + sw);
        *(ushort8v*)(Opb + (qbaseA + row) * DD + chunk * 8) = valA;
        *(ushort8v*)(Opb + (qbaseB + row) * DD + chunk * 8) = valB;
    }
}

// ---------------- combine: O = sum_sp(Opb) / sum_sp(Lp); branchless 4-way ----------------
__global__ __launch_bounds__(512) void k_combine(
    const unsigned short* __restrict__ Opb, const float* __restrict__ Lp,
    float* __restrict__ Og)
{
    const int idx = (int)(blockIdx.x * 512 + threadIdx.x);   // 8-elem group, NH*QL*DD/8 = 262144
    const int d8 = idx & 7;
    const int q  = (idx >> 3) & (QL - 1);
    const int n  = idx >> 14;
    float s[8];
    #pragma unroll
    for (int j = 0; j < 8; ++j) s[j] = 0.f;
    float l = 0.f;
    #pragma unroll
    for (int sp = 0; sp < NSPLIT; ++sp) {      // parity-4 split: all ALWAYS contribute
        const unsigned short* ob = Opb + (((size_t)sp * NH + n) * QL + q) * DD + d8 * 8;
        ushort8v v = *(const ushort8v*)ob;
        #pragma unroll
        for (int j = 0; j < 8; ++j) s[j] += bf2f(v[j]);
        l += Lp[((size_t)sp * NH + n) * QL + q];
    }
    const float inv = 1.0f / l;                // l > 0: diag col always unmasked in its split
    float4 o0 = { s[0] * inv, s[1] * inv, s[2] * inv, s[3] * inv };
    float4 o1 = { s[4] * inv, s[5] * inv, s[6] * inv, s[7] * inv };
    float* og = Og + ((size_t)n * QL + q) * DD + d8 * 8;
    *(float4*)og = o0;
    *(float4*)(og + 4) = o1;
}

extern "C" void kernel_launch(void* const* d_in, const int* in_sizes, int n_in,
                              void* d_out, int out_size, void* d_ws, size_t ws_size,
                              hipStream_t stream) {
    const float* Qf   = (const float*)d_in[0];
    const float* Kf   = (const float*)d_in[1];
    const float* Vf   = (const float*)d_in[2];
    const int*   plen = (const int*)d_in[3];
    float* Og = (float*)d_out;

    char* ws = (char*)d_ws;
    unsigned short* Kb  = (unsigned short*)(ws);                 // 4 MB
    unsigned short* Vtb = (unsigned short*)(ws + (4u << 20));    // 4 MB
    unsigned short* Qb  = (unsigned short*)(ws + (8u << 20));    // 4 MB
    unsigned short* Opb = (unsigned short*)(ws + (12u << 20));   // NSPLIT * 4 MB = 16 MB
    float*          Lp  = (float*)(ws + (28u << 20));            // NSPLIT * 128 KB

    k_prep<<<512, 512, 0, stream>>>(Qf, Kf, Vf, Qb, Kb, Vtb);
    k_attn<<<NSPLIT * 128, 512, 0, stream>>>(Qb, Kb, Vtb, plen, Opb, Lp);
    k_combine<<<512, 512, 0, stream>>>(Opb, Lp, Og);
}